// Round 1
// baseline (298.920 us; speedup 1.0000x reference)
//
#include <hip/hip_runtime.h>
#include <math.h>

#define EPS 1e-8f
#define HALF_BIN 0.05f

__device__ __forceinline__ float fast_sigmoid(float x) {
    // sigmoid(x) = 1/(1+exp(-x)); __expf -> v_exp_f32, __frcp via fast divide
    return __fdividef(1.0f, 1.0f + __expf(-x));
}

// acc[0] = sum of per-element BCE loss contributions (to be divided by B)
// acc[1] = ll_sum  (sum of log_likelihood over paid elements)
// acc[2] = n_paid
template <int K>
__global__ __launch_bounds__(256) void zimol_main(
    const float* __restrict__ p,
    const float* __restrict__ mu,
    const float* __restrict__ sigma,
    const float* __restrict__ weight,
    const float* __restrict__ tv,
    double* __restrict__ acc,
    int B)
{
    const int tid    = blockIdx.x * blockDim.x + threadIdx.x;
    const int stride = gridDim.x * blockDim.x;
    const int B4 = B >> 2;

    const float4* __restrict__ p4  = (const float4*)p;
    const float4* __restrict__ tv4 = (const float4*)tv;

    float bce = 0.0f, ll = 0.0f, npaid = 0.0f;

    for (int i = tid; i < B4; i += stride) {
        float4 pf = p4[i];
        float4 tf = tv4[i];
        float pv[4] = {pf.x, pf.y, pf.z, pf.w};
        float t [4] = {tf.x, tf.y, tf.z, tf.w};
        float lik[4] = {0.0f, 0.0f, 0.0f, 0.0f};

        #pragma unroll
        for (int k = 0; k < K; ++k) {
            const size_t off = (size_t)k * (size_t)B;
            float4 mf = ((const float4*)(mu     + off))[i];
            float4 sf = ((const float4*)(sigma  + off))[i];
            float4 wf = ((const float4*)(weight + off))[i];
            float m[4] = {mf.x, mf.y, mf.z, mf.w};
            float s[4] = {sf.x, sf.y, sf.z, sf.w};
            float w[4] = {wf.x, wf.y, wf.z, wf.w};
            #pragma unroll
            for (int j = 0; j < 4; ++j) {
                float inv_s = __fdividef(1.0f, s[j] + EPS);
                float cu = fast_sigmoid((t[j] + HALF_BIN - m[j]) * inv_s);
                float cl = fast_sigmoid((t[j] - HALF_BIN - m[j]) * inv_s);
                float pd = fmaxf(cu - cl, EPS);
                lik[j] = fmaf(w[j], pd, lik[j]);
            }
        }

        #pragma unroll
        for (int j = 0; j < 4; ++j) {
            float target  = (t[j] > 0.0f) ? 1.0f : 0.0f;
            float log_p   = fmaxf(__logf(pv[j]),        -100.0f);
            float log_1mp = fmaxf(__logf(1.0f - pv[j]), -100.0f);
            bce -= target * log_p + (1.0f - target) * log_1mp;
            if (t[j] > 0.0f) {
                ll    += __logf(lik[j] + EPS);
                npaid += 1.0f;
            }
        }
    }

    // wave-level reduction (wave = 64 lanes)
    #pragma unroll
    for (int off = 32; off > 0; off >>= 1) {
        bce   += __shfl_down(bce,   off, 64);
        ll    += __shfl_down(ll,    off, 64);
        npaid += __shfl_down(npaid, off, 64);
    }

    __shared__ float sdata[3][4];
    const int wave = threadIdx.x >> 6;
    const int lane = threadIdx.x & 63;
    if (lane == 0) {
        sdata[0][wave] = bce;
        sdata[1][wave] = ll;
        sdata[2][wave] = npaid;
    }
    __syncthreads();
    if (threadIdx.x == 0) {
        float b = 0.0f, l = 0.0f, n = 0.0f;
        #pragma unroll
        for (int w = 0; w < 4; ++w) {
            b += sdata[0][w];
            l += sdata[1][w];
            n += sdata[2][w];
        }
        atomicAdd(&acc[0], (double)b);
        atomicAdd(&acc[1], (double)l);
        atomicAdd(&acc[2], (double)n);
    }
}

__global__ void zimol_final(const double* __restrict__ acc,
                            float* __restrict__ out, int B)
{
    double purchase = acc[0] / (double)B;
    double npaid = acc[2];
    double ltv = (npaid > 0.0) ? -(acc[1] / fmax(npaid, 1.0)) : 0.0;
    out[0] = (float)(purchase + ltv);
}

extern "C" void kernel_launch(void* const* d_in, const int* in_sizes, int n_in,
                              void* d_out, int out_size, void* d_ws, size_t ws_size,
                              hipStream_t stream) {
    const float* p      = (const float*)d_in[0];
    const float* mu     = (const float*)d_in[1];
    const float* sigma  = (const float*)d_in[2];
    const float* weight = (const float*)d_in[3];
    const float* tv     = (const float*)d_in[4];
    float* out = (float*)d_out;

    const int B = in_sizes[0];
    const int K = in_sizes[1] / B;

    double* acc = (double*)d_ws;
    hipMemsetAsync(acc, 0, 3 * sizeof(double), stream);

    const int threads = 256;
    int blocks = (B / 4 + threads - 1) / threads;   // one float4 per thread
    if (blocks < 1) blocks = 1;

    if (K == 3) {
        zimol_main<3><<<blocks, threads, 0, stream>>>(p, mu, sigma, weight, tv, acc, B);
    } else if (K == 1) {
        zimol_main<1><<<blocks, threads, 0, stream>>>(p, mu, sigma, weight, tv, acc, B);
    } else if (K == 2) {
        zimol_main<2><<<blocks, threads, 0, stream>>>(p, mu, sigma, weight, tv, acc, B);
    } else {
        zimol_main<4><<<blocks, threads, 0, stream>>>(p, mu, sigma, weight, tv, acc, B);
    }

    zimol_final<<<1, 1, 0, stream>>>(acc, out, B);
}

// Round 2
// 195.744 us; speedup vs baseline: 1.5271x; 1.5271x over previous
//
#include <hip/hip_runtime.h>
#include <math.h>

#define EPS 1e-8f
#define HALF_BIN 0.05f

__device__ __forceinline__ float fast_sigmoid(float x) {
    return __fdividef(1.0f, 1.0f + __expf(-x));
}

// Per-block partials written to SoA arrays (no atomics):
//   part_bce[b], part_ll[b], part_n[b]
template <int K>
__global__ __launch_bounds__(256) void zimol_main(
    const float* __restrict__ p,
    const float* __restrict__ mu,
    const float* __restrict__ sigma,
    const float* __restrict__ weight,
    const float* __restrict__ tv,
    float* __restrict__ part_bce,
    float* __restrict__ part_ll,
    float* __restrict__ part_n,
    int B)
{
    const int tid    = blockIdx.x * blockDim.x + threadIdx.x;
    const int stride = gridDim.x * blockDim.x;
    const int B4 = B >> 2;

    const float4* __restrict__ p4  = (const float4*)p;
    const float4* __restrict__ tv4 = (const float4*)tv;

    float bce = 0.0f, ll = 0.0f, npaid = 0.0f;

    for (int i = tid; i < B4; i += stride) {
        float4 pf = p4[i];
        float4 tf = tv4[i];
        float pv[4] = {pf.x, pf.y, pf.z, pf.w};
        float t [4] = {tf.x, tf.y, tf.z, tf.w};
        float lik[4] = {0.0f, 0.0f, 0.0f, 0.0f};

        #pragma unroll
        for (int k = 0; k < K; ++k) {
            const size_t off = (size_t)k * (size_t)B;
            float4 mf = ((const float4*)(mu     + off))[i];
            float4 sf = ((const float4*)(sigma  + off))[i];
            float4 wf = ((const float4*)(weight + off))[i];
            float m[4] = {mf.x, mf.y, mf.z, mf.w};
            float s[4] = {sf.x, sf.y, sf.z, sf.w};
            float w[4] = {wf.x, wf.y, wf.z, wf.w};
            #pragma unroll
            for (int j = 0; j < 4; ++j) {
                float inv_s = __fdividef(1.0f, s[j] + EPS);
                float cu = fast_sigmoid((t[j] + HALF_BIN - m[j]) * inv_s);
                float cl = fast_sigmoid((t[j] - HALF_BIN - m[j]) * inv_s);
                float pd = fmaxf(cu - cl, EPS);
                lik[j] = fmaf(w[j], pd, lik[j]);
            }
        }

        #pragma unroll
        for (int j = 0; j < 4; ++j) {
            float target  = (t[j] > 0.0f) ? 1.0f : 0.0f;
            float log_p   = fmaxf(__logf(pv[j]),        -100.0f);
            float log_1mp = fmaxf(__logf(1.0f - pv[j]), -100.0f);
            bce -= target * log_p + (1.0f - target) * log_1mp;
            if (t[j] > 0.0f) {
                ll    += __logf(lik[j] + EPS);
                npaid += 1.0f;
            }
        }
    }

    // scalar tail (B not divisible by 4) — handled by global thread 0
    if (tid == 0) {
        for (int i = B4 << 2; i < B; ++i) {
            float t = tv[i];
            float lik0 = 0.0f;
            #pragma unroll
            for (int k = 0; k < K; ++k) {
                const size_t off = (size_t)k * (size_t)B + i;
                float inv_s = __fdividef(1.0f, sigma[off] + EPS);
                float cu = fast_sigmoid((t + HALF_BIN - mu[off]) * inv_s);
                float cl = fast_sigmoid((t - HALF_BIN - mu[off]) * inv_s);
                lik0 = fmaf(weight[off], fmaxf(cu - cl, EPS), lik0);
            }
            float target  = (t > 0.0f) ? 1.0f : 0.0f;
            float log_p   = fmaxf(__logf(p[i]),        -100.0f);
            float log_1mp = fmaxf(__logf(1.0f - p[i]), -100.0f);
            bce -= target * log_p + (1.0f - target) * log_1mp;
            if (t > 0.0f) { ll += __logf(lik0 + EPS); npaid += 1.0f; }
        }
    }

    // wave-level reduction (wave = 64 lanes)
    #pragma unroll
    for (int off = 32; off > 0; off >>= 1) {
        bce   += __shfl_down(bce,   off, 64);
        ll    += __shfl_down(ll,    off, 64);
        npaid += __shfl_down(npaid, off, 64);
    }

    __shared__ float sdata[3][4];
    const int wave = threadIdx.x >> 6;
    const int lane = threadIdx.x & 63;
    if (lane == 0) {
        sdata[0][wave] = bce;
        sdata[1][wave] = ll;
        sdata[2][wave] = npaid;
    }
    __syncthreads();
    if (threadIdx.x == 0) {
        float b = 0.0f, l = 0.0f, n = 0.0f;
        #pragma unroll
        for (int w = 0; w < 4; ++w) {
            b += sdata[0][w];
            l += sdata[1][w];
            n += sdata[2][w];
        }
        part_bce[blockIdx.x] = b;
        part_ll [blockIdx.x] = l;
        part_n  [blockIdx.x] = n;
    }
}

__global__ __launch_bounds__(256) void zimol_reduce(
    const float* __restrict__ part_bce,
    const float* __restrict__ part_ll,
    const float* __restrict__ part_n,
    float* __restrict__ out, int nblocks, int B)
{
    double b = 0.0, l = 0.0, n = 0.0;
    for (int i = threadIdx.x; i < nblocks; i += 256) {
        b += (double)part_bce[i];
        l += (double)part_ll[i];
        n += (double)part_n[i];
    }
    #pragma unroll
    for (int off = 32; off > 0; off >>= 1) {
        b += __shfl_down(b, off, 64);
        l += __shfl_down(l, off, 64);
        n += __shfl_down(n, off, 64);
    }
    __shared__ double sdata[3][4];
    const int wave = threadIdx.x >> 6;
    const int lane = threadIdx.x & 63;
    if (lane == 0) {
        sdata[0][wave] = b;
        sdata[1][wave] = l;
        sdata[2][wave] = n;
    }
    __syncthreads();
    if (threadIdx.x == 0) {
        double tb = 0.0, tl = 0.0, tn = 0.0;
        #pragma unroll
        for (int w = 0; w < 4; ++w) {
            tb += sdata[0][w];
            tl += sdata[1][w];
            tn += sdata[2][w];
        }
        double purchase = tb / (double)B;
        double ltv = (tn > 0.0) ? -(tl / fmax(tn, 1.0)) : 0.0;
        out[0] = (float)(purchase + ltv);
    }
}

extern "C" void kernel_launch(void* const* d_in, const int* in_sizes, int n_in,
                              void* d_out, int out_size, void* d_ws, size_t ws_size,
                              hipStream_t stream) {
    const float* p      = (const float*)d_in[0];
    const float* mu     = (const float*)d_in[1];
    const float* sigma  = (const float*)d_in[2];
    const float* weight = (const float*)d_in[3];
    const float* tv     = (const float*)d_in[4];
    float* out = (float*)d_out;

    const int B = in_sizes[0];
    const int K = in_sizes[1] / B;

    const int threads = 256;
    int blocks = ((B >> 2) + threads - 1) / threads;   // one float4 per thread
    if (blocks < 1) blocks = 1;
    if (blocks > 65536) blocks = 65536;

    float* part_bce = (float*)d_ws;
    float* part_ll  = part_bce + blocks;
    float* part_n   = part_ll  + blocks;

    if (K == 3) {
        zimol_main<3><<<blocks, threads, 0, stream>>>(p, mu, sigma, weight, tv,
                                                      part_bce, part_ll, part_n, B);
    } else if (K == 1) {
        zimol_main<1><<<blocks, threads, 0, stream>>>(p, mu, sigma, weight, tv,
                                                      part_bce, part_ll, part_n, B);
    } else if (K == 2) {
        zimol_main<2><<<blocks, threads, 0, stream>>>(p, mu, sigma, weight, tv,
                                                      part_bce, part_ll, part_n, B);
    } else {
        zimol_main<4><<<blocks, threads, 0, stream>>>(p, mu, sigma, weight, tv,
                                                      part_bce, part_ll, part_n, B);
    }

    zimol_reduce<<<1, threads, 0, stream>>>(part_bce, part_ll, part_n, out, blocks, B);
}

// Round 3
// 193.779 us; speedup vs baseline: 1.5426x; 1.0101x over previous
//
#include <hip/hip_runtime.h>
#include <math.h>

#define EPS 1e-8f
#define HALF_BIN 0.05f

// pd = sigmoid(xu) - sigmoid(xl), xu >= xl, computed with one reciprocal:
//   e_u = exp(-xu), e_l = exp(-xl)
//   pd  = (e_l - e_u) / ((1+e_u)(1+e_l))
// exp args clamped to <= 87 so e is finite (<= 6.1e37); saturated cases give
// den -> inf -> rcp 0 -> pd 0, matching the reference's (0 - 0) there.
__device__ __forceinline__ float sigmoid_diff(float xu, float xl) {
    float eu = __expf(fminf(-xu, 87.0f));
    float el = __expf(fminf(-xl, 87.0f));
    float num = el - eu;
    float den = (1.0f + eu) * (1.0f + el);
    return __fdividef(num, den);
}

template <int K>
__device__ __forceinline__ void process_group(
    const float4& pf, const float4& tf,
    const float4 (&mf)[K], const float4 (&sf)[K], const float4 (&wf)[K],
    float& bce, float& ll, float& npaid)
{
    float pv[4] = {pf.x, pf.y, pf.z, pf.w};
    float t [4] = {tf.x, tf.y, tf.z, tf.w};
    float lik[4] = {0.0f, 0.0f, 0.0f, 0.0f};

    #pragma unroll
    for (int k = 0; k < K; ++k) {
        float m[4] = {mf[k].x, mf[k].y, mf[k].z, mf[k].w};
        float s[4] = {sf[k].x, sf[k].y, sf[k].z, sf[k].w};
        float w[4] = {wf[k].x, wf[k].y, wf[k].z, wf[k].w};
        #pragma unroll
        for (int j = 0; j < 4; ++j) {
            float inv_s = __fdividef(1.0f, s[j] + EPS);
            float xu = (t[j] + HALF_BIN - m[j]) * inv_s;
            float xl = (t[j] - HALF_BIN - m[j]) * inv_s;
            float pd = fmaxf(sigmoid_diff(xu, xl), EPS);
            lik[j] = fmaf(w[j], pd, lik[j]);
        }
    }

    #pragma unroll
    for (int j = 0; j < 4; ++j) {
        bool paid = t[j] > 0.0f;
        float val = paid ? pv[j] : (1.0f - pv[j]);
        bce -= fmaxf(__logf(val), -100.0f);
        float lg = __logf(lik[j] + EPS);
        ll    += paid ? lg : 0.0f;
        npaid += paid ? 1.0f : 0.0f;
    }
}

template <int K>
__device__ __forceinline__ void process_elem(
    float pv, float t, const float* mu, const float* sigma, const float* weight,
    size_t i, size_t B, float& bce, float& ll, float& npaid)
{
    float lik = 0.0f;
    #pragma unroll
    for (int k = 0; k < K; ++k) {
        size_t off = (size_t)k * B + i;
        float inv_s = __fdividef(1.0f, sigma[off] + EPS);
        float xu = (t + HALF_BIN - mu[off]) * inv_s;
        float xl = (t - HALF_BIN - mu[off]) * inv_s;
        float pd = fmaxf(sigmoid_diff(xu, xl), EPS);
        lik = fmaf(weight[off], pd, lik);
    }
    bool paid = t > 0.0f;
    float val = paid ? pv : (1.0f - pv);
    bce -= fmaxf(__logf(val), -100.0f);
    float lg = __logf(lik + EPS);
    ll    += paid ? lg : 0.0f;
    npaid += paid ? 1.0f : 0.0f;
}

template <int K>
__global__ __launch_bounds__(256) void zimol_main(
    const float* __restrict__ p,
    const float* __restrict__ mu,
    const float* __restrict__ sigma,
    const float* __restrict__ weight,
    const float* __restrict__ tv,
    float* __restrict__ part_bce,
    float* __restrict__ part_ll,
    float* __restrict__ part_n,
    int B)
{
    const int tid    = blockIdx.x * blockDim.x + threadIdx.x;
    const int stride = gridDim.x * blockDim.x;

    float bce = 0.0f, ll = 0.0f, npaid = 0.0f;

    if ((B & 3) == 0) {
        const int B4 = B >> 2;
        const float4* __restrict__ p4  = (const float4*)p;
        const float4* __restrict__ tv4 = (const float4*)tv;
        const float4* __restrict__ mu4 = (const float4*)mu;
        const float4* __restrict__ sg4 = (const float4*)sigma;
        const float4* __restrict__ wt4 = (const float4*)weight;

        int i = tid;
        // two independent float4-groups per trip: 22 loads in flight
        for (; i + stride < B4; i += 2 * stride) {
            const int i0 = i, i1 = i + stride;
            float4 pf0  = p4[i0],  pf1  = p4[i1];
            float4 tf0  = tv4[i0], tf1  = tv4[i1];
            float4 mf0[K], sf0[K], wf0[K];
            float4 mf1[K], sf1[K], wf1[K];
            #pragma unroll
            for (int k = 0; k < K; ++k) {
                const size_t off = (size_t)k * (size_t)B4;  // float4 units
                mf0[k] = mu4[off + i0];  mf1[k] = mu4[off + i1];
                sf0[k] = sg4[off + i0];  sf1[k] = sg4[off + i1];
                wf0[k] = wt4[off + i0];  wf1[k] = wt4[off + i1];
            }
            process_group<K>(pf0, tf0, mf0, sf0, wf0, bce, ll, npaid);
            process_group<K>(pf1, tf1, mf1, sf1, wf1, bce, ll, npaid);
        }
        // remaining single groups
        for (; i < B4; i += stride) {
            float4 pf = p4[i], tf = tv4[i];
            float4 mf[K], sf[K], wf[K];
            #pragma unroll
            for (int k = 0; k < K; ++k) {
                const size_t off = (size_t)k * (size_t)B4;
                mf[k] = mu4[off + i];
                sf[k] = sg4[off + i];
                wf[k] = wt4[off + i];
            }
            process_group<K>(pf, tf, mf, sf, wf, bce, ll, npaid);
        }
    } else {
        for (int i = tid; i < B; i += stride) {
            process_elem<K>(p[i], tv[i], mu, sigma, weight,
                            (size_t)i, (size_t)B, bce, ll, npaid);
        }
    }

    // wave-level reduction (wave = 64 lanes)
    #pragma unroll
    for (int off = 32; off > 0; off >>= 1) {
        bce   += __shfl_down(bce,   off, 64);
        ll    += __shfl_down(ll,    off, 64);
        npaid += __shfl_down(npaid, off, 64);
    }

    __shared__ float sdata[3][4];
    const int wave = threadIdx.x >> 6;
    const int lane = threadIdx.x & 63;
    if (lane == 0) {
        sdata[0][wave] = bce;
        sdata[1][wave] = ll;
        sdata[2][wave] = npaid;
    }
    __syncthreads();
    if (threadIdx.x == 0) {
        float b = 0.0f, l = 0.0f, n = 0.0f;
        #pragma unroll
        for (int w = 0; w < 4; ++w) {
            b += sdata[0][w];
            l += sdata[1][w];
            n += sdata[2][w];
        }
        part_bce[blockIdx.x] = b;
        part_ll [blockIdx.x] = l;
        part_n  [blockIdx.x] = n;
    }
}

__global__ __launch_bounds__(256) void zimol_reduce(
    const float* __restrict__ part_bce,
    const float* __restrict__ part_ll,
    const float* __restrict__ part_n,
    float* __restrict__ out, int nblocks, int B)
{
    double b = 0.0, l = 0.0, n = 0.0;
    for (int i = threadIdx.x; i < nblocks; i += 256) {
        b += (double)part_bce[i];
        l += (double)part_ll[i];
        n += (double)part_n[i];
    }
    #pragma unroll
    for (int off = 32; off > 0; off >>= 1) {
        b += __shfl_down(b, off, 64);
        l += __shfl_down(l, off, 64);
        n += __shfl_down(n, off, 64);
    }
    __shared__ double sdata[3][4];
    const int wave = threadIdx.x >> 6;
    const int lane = threadIdx.x & 63;
    if (lane == 0) {
        sdata[0][wave] = b;
        sdata[1][wave] = l;
        sdata[2][wave] = n;
    }
    __syncthreads();
    if (threadIdx.x == 0) {
        double tb = 0.0, tl = 0.0, tn = 0.0;
        #pragma unroll
        for (int w = 0; w < 4; ++w) {
            tb += sdata[0][w];
            tl += sdata[1][w];
            tn += sdata[2][w];
        }
        double purchase = tb / (double)B;
        double ltv = (tn > 0.0) ? -(tl / fmax(tn, 1.0)) : 0.0;
        out[0] = (float)(purchase + ltv);
    }
}

extern "C" void kernel_launch(void* const* d_in, const int* in_sizes, int n_in,
                              void* d_out, int out_size, void* d_ws, size_t ws_size,
                              hipStream_t stream) {
    const float* p      = (const float*)d_in[0];
    const float* mu     = (const float*)d_in[1];
    const float* sigma  = (const float*)d_in[2];
    const float* weight = (const float*)d_in[3];
    const float* tv     = (const float*)d_in[4];
    float* out = (float*)d_out;

    const int B = in_sizes[0];
    const int K = in_sizes[1] / B;

    const int threads = 256;
    // 1024 blocks = 4 blocks/CU resident at ~110 VGPR; each thread does
    // 4 float4-groups (2 trips x 2-way ILP) at B = 4M.
    int work = ((B + 3) >> 2);
    int blocks = (work + threads - 1) / threads;
    if (blocks > 1024) blocks = 1024;
    if (blocks < 1) blocks = 1;

    float* part_bce = (float*)d_ws;
    float* part_ll  = part_bce + blocks;
    float* part_n   = part_ll  + blocks;

    if (K == 3) {
        zimol_main<3><<<blocks, threads, 0, stream>>>(p, mu, sigma, weight, tv,
                                                      part_bce, part_ll, part_n, B);
    } else if (K == 1) {
        zimol_main<1><<<blocks, threads, 0, stream>>>(p, mu, sigma, weight, tv,
                                                      part_bce, part_ll, part_n, B);
    } else if (K == 2) {
        zimol_main<2><<<blocks, threads, 0, stream>>>(p, mu, sigma, weight, tv,
                                                      part_bce, part_ll, part_n, B);
    } else {
        zimol_main<4><<<blocks, threads, 0, stream>>>(p, mu, sigma, weight, tv,
                                                      part_bce, part_ll, part_n, B);
    }

    zimol_reduce<<<1, threads, 0, stream>>>(part_bce, part_ll, part_n, out, blocks, B);
}

// Round 4
// 193.294 us; speedup vs baseline: 1.5465x; 1.0025x over previous
//
#include <hip/hip_runtime.h>
#include <math.h>

#define EPS 1e-8f
#define HALF_BIN 0.05f

// pd = sigmoid(xu) - sigmoid(xl), xu >= xl, computed with one reciprocal:
//   e_u = exp(-xu), e_l = exp(-xl)
//   pd  = (e_l - e_u) / ((1+e_u)(1+e_l))
// exp args clamped to <= 87 so e is finite; saturated cases give den->inf ->
// rcp 0 -> pd 0, matching the reference's (0 - 0) there.
__device__ __forceinline__ float sigmoid_diff(float xu, float xl) {
    float eu = __expf(fminf(-xu, 87.0f));
    float el = __expf(fminf(-xl, 87.0f));
    float num = el - eu;
    float den = (1.0f + eu) * (1.0f + el);
    return __fdividef(num, den);
}

// buf layout per group: [0]=p, [1]=tv, then for k: [2+3k]=mu, [3+3k]=sigma, [4+3k]=weight
template <int K>
__device__ __forceinline__ void process_group_buf(
    const float4 (&buf)[3 * K + 2],
    float& bce, float& ll, float& npaid)
{
    float pv[4] = {buf[0].x, buf[0].y, buf[0].z, buf[0].w};
    float t [4] = {buf[1].x, buf[1].y, buf[1].z, buf[1].w};
    float lik[4] = {0.0f, 0.0f, 0.0f, 0.0f};

    #pragma unroll
    for (int k = 0; k < K; ++k) {
        const float4 mf = buf[2 + 3 * k];
        const float4 sf = buf[3 + 3 * k];
        const float4 wf = buf[4 + 3 * k];
        float m[4] = {mf.x, mf.y, mf.z, mf.w};
        float s[4] = {sf.x, sf.y, sf.z, sf.w};
        float w[4] = {wf.x, wf.y, wf.z, wf.w};
        #pragma unroll
        for (int j = 0; j < 4; ++j) {
            float inv_s = __fdividef(1.0f, s[j] + EPS);
            float xu = (t[j] + HALF_BIN - m[j]) * inv_s;
            float xl = (t[j] - HALF_BIN - m[j]) * inv_s;
            float pd = fmaxf(sigmoid_diff(xu, xl), EPS);
            lik[j] = fmaf(w[j], pd, lik[j]);
        }
    }

    #pragma unroll
    for (int j = 0; j < 4; ++j) {
        bool paid = t[j] > 0.0f;
        float val = paid ? pv[j] : (1.0f - pv[j]);
        bce -= fmaxf(__logf(val), -100.0f);
        float lg = __logf(lik[j] + EPS);
        ll    += paid ? lg : 0.0f;
        npaid += paid ? 1.0f : 0.0f;
    }
}

template <int K>
__device__ __forceinline__ void process_elem(
    float pv, float t, const float* mu, const float* sigma, const float* weight,
    size_t i, size_t B, float& bce, float& ll, float& npaid)
{
    float lik = 0.0f;
    #pragma unroll
    for (int k = 0; k < K; ++k) {
        size_t off = (size_t)k * B + i;
        float inv_s = __fdividef(1.0f, sigma[off] + EPS);
        float xu = (t + HALF_BIN - mu[off]) * inv_s;
        float xl = (t - HALF_BIN - mu[off]) * inv_s;
        float pd = fmaxf(sigmoid_diff(xu, xl), EPS);
        lik = fmaf(weight[off], pd, lik);
    }
    bool paid = t > 0.0f;
    float val = paid ? pv : (1.0f - pv);
    bce -= fmaxf(__logf(val), -100.0f);
    float lg = __logf(lik + EPS);
    ll    += paid ? lg : 0.0f;
    npaid += paid ? 1.0f : 0.0f;
}

// __launch_bounds__(256, 4): 4 waves/EU min -> VGPR budget 128 (not 40).
// This is the license the compiler needs to keep all 22 float4 loads of a
// trip in flight instead of serializing them into one-register batches.
template <int K>
__global__ __launch_bounds__(256, 4) void zimol_main(
    const float* __restrict__ p,
    const float* __restrict__ mu,
    const float* __restrict__ sigma,
    const float* __restrict__ weight,
    const float* __restrict__ tv,
    float* __restrict__ part_bce,
    float* __restrict__ part_ll,
    float* __restrict__ part_n,
    int B)
{
    const int tid    = blockIdx.x * blockDim.x + threadIdx.x;
    const int stride = gridDim.x * blockDim.x;

    float bce = 0.0f, ll = 0.0f, npaid = 0.0f;

    if ((B & 3) == 0) {
        const int B4 = B >> 2;
        const float4* __restrict__ p4  = (const float4*)p;
        const float4* __restrict__ tv4 = (const float4*)tv;
        const float4* __restrict__ mu4 = (const float4*)mu;
        const float4* __restrict__ sg4 = (const float4*)sigma;
        const float4* __restrict__ wt4 = (const float4*)weight;

        constexpr int NB = 3 * K + 2;   // float4s per group
        int i = tid;
        // two independent groups per trip; all 2*NB loads issued before compute
        for (; i + stride < B4; i += 2 * stride) {
            float4 buf[2][NB];
            #pragma unroll
            for (int u = 0; u < 2; ++u) {
                const int idx = i + u * stride;
                buf[u][0] = p4[idx];
                buf[u][1] = tv4[idx];
                #pragma unroll
                for (int k = 0; k < K; ++k) {
                    const size_t off = (size_t)k * (size_t)B4;
                    buf[u][2 + 3 * k] = mu4[off + idx];
                    buf[u][3 + 3 * k] = sg4[off + idx];
                    buf[u][4 + 3 * k] = wt4[off + idx];
                }
            }
            process_group_buf<K>(buf[0], bce, ll, npaid);
            process_group_buf<K>(buf[1], bce, ll, npaid);
        }
        // remaining single groups
        for (; i < B4; i += stride) {
            float4 buf[NB];
            buf[0] = p4[i];
            buf[1] = tv4[i];
            #pragma unroll
            for (int k = 0; k < K; ++k) {
                const size_t off = (size_t)k * (size_t)B4;
                buf[2 + 3 * k] = mu4[off + i];
                buf[3 + 3 * k] = sg4[off + i];
                buf[4 + 3 * k] = wt4[off + i];
            }
            process_group_buf<K>(buf, bce, ll, npaid);
        }
    } else {
        for (int i = tid; i < B; i += stride) {
            process_elem<K>(p[i], tv[i], mu, sigma, weight,
                            (size_t)i, (size_t)B, bce, ll, npaid);
        }
    }

    // wave-level reduction (wave = 64 lanes)
    #pragma unroll
    for (int off = 32; off > 0; off >>= 1) {
        bce   += __shfl_down(bce,   off, 64);
        ll    += __shfl_down(ll,    off, 64);
        npaid += __shfl_down(npaid, off, 64);
    }

    __shared__ float sdata[3][4];
    const int wave = threadIdx.x >> 6;
    const int lane = threadIdx.x & 63;
    if (lane == 0) {
        sdata[0][wave] = bce;
        sdata[1][wave] = ll;
        sdata[2][wave] = npaid;
    }
    __syncthreads();
    if (threadIdx.x == 0) {
        float b = 0.0f, l = 0.0f, n = 0.0f;
        #pragma unroll
        for (int w = 0; w < 4; ++w) {
            b += sdata[0][w];
            l += sdata[1][w];
            n += sdata[2][w];
        }
        part_bce[blockIdx.x] = b;
        part_ll [blockIdx.x] = l;
        part_n  [blockIdx.x] = n;
    }
}

__global__ __launch_bounds__(256) void zimol_reduce(
    const float* __restrict__ part_bce,
    const float* __restrict__ part_ll,
    const float* __restrict__ part_n,
    float* __restrict__ out, int nblocks, int B)
{
    double b = 0.0, l = 0.0, n = 0.0;
    for (int i = threadIdx.x; i < nblocks; i += 256) {
        b += (double)part_bce[i];
        l += (double)part_ll[i];
        n += (double)part_n[i];
    }
    #pragma unroll
    for (int off = 32; off > 0; off >>= 1) {
        b += __shfl_down(b, off, 64);
        l += __shfl_down(l, off, 64);
        n += __shfl_down(n, off, 64);
    }
    __shared__ double sdata[3][4];
    const int wave = threadIdx.x >> 6;
    const int lane = threadIdx.x & 63;
    if (lane == 0) {
        sdata[0][wave] = b;
        sdata[1][wave] = l;
        sdata[2][wave] = n;
    }
    __syncthreads();
    if (threadIdx.x == 0) {
        double tb = 0.0, tl = 0.0, tn = 0.0;
        #pragma unroll
        for (int w = 0; w < 4; ++w) {
            tb += sdata[0][w];
            tl += sdata[1][w];
            tn += sdata[2][w];
        }
        double purchase = tb / (double)B;
        double ltv = (tn > 0.0) ? -(tl / fmax(tn, 1.0)) : 0.0;
        out[0] = (float)(purchase + ltv);
    }
}

extern "C" void kernel_launch(void* const* d_in, const int* in_sizes, int n_in,
                              void* d_out, int out_size, void* d_ws, size_t ws_size,
                              hipStream_t stream) {
    const float* p      = (const float*)d_in[0];
    const float* mu     = (const float*)d_in[1];
    const float* sigma  = (const float*)d_in[2];
    const float* weight = (const float*)d_in[3];
    const float* tv     = (const float*)d_in[4];
    float* out = (float*)d_out;

    const int B = in_sizes[0];
    const int K = in_sizes[1] / B;

    const int threads = 256;
    // 1024 blocks: B4=1M -> 4 float4-groups/thread = 2 trips of the
    // 2-way-ILP loop; 4 blocks/CU resident at <=128 VGPR.
    int work = ((B + 3) >> 2);
    int blocks = (work + threads - 1) / threads;
    if (blocks > 1024) blocks = 1024;
    if (blocks < 1) blocks = 1;

    float* part_bce = (float*)d_ws;
    float* part_ll  = part_bce + blocks;
    float* part_n   = part_ll  + blocks;

    if (K == 3) {
        zimol_main<3><<<blocks, threads, 0, stream>>>(p, mu, sigma, weight, tv,
                                                      part_bce, part_ll, part_n, B);
    } else if (K == 1) {
        zimol_main<1><<<blocks, threads, 0, stream>>>(p, mu, sigma, weight, tv,
                                                      part_bce, part_ll, part_n, B);
    } else if (K == 2) {
        zimol_main<2><<<blocks, threads, 0, stream>>>(p, mu, sigma, weight, tv,
                                                      part_bce, part_ll, part_n, B);
    } else {
        zimol_main<4><<<blocks, threads, 0, stream>>>(p, mu, sigma, weight, tv,
                                                      part_bce, part_ll, part_n, B);
    }

    zimol_reduce<<<1, threads, 0, stream>>>(part_bce, part_ll, part_n, out, blocks, B);
}